// Round 2
// baseline (370.327 us; speedup 1.0000x reference)
//
#include <hip/hip_runtime.h>

#define GDIM 128
#define NS   128
#define VD   28

__global__ __launch_bounds__(512, 4) void plenoxel_kernel(
    const float* __restrict__ grid,
    const float* __restrict__ pos,
    const float* __restrict__ dist,
    const float* __restrict__ ang,
    float* __restrict__ out)
{
    const int r   = blockIdx.x;
    const int tid = threadIdx.x;
    const int s   = tid & (NS - 1);   // sample 0..127
    const int p   = tid >> 7;         // corner-pair 0..3 -> (dx, dy)
    const int dx  = p >> 1;
    const int dy  = p & 1;
    const int lane = tid & 63;

    // ---- SH basis (redundant per thread; VALU-cheap, hides under loads) ----
    const float th = ang[2 * r + 0];
    const float ph = ang[2 * r + 1];
    float st, ct, sp, cp;
    sincosf(th, &st, &ct);
    sincosf(ph, &sp, &cp);
    const float Y00 = 0.28209479177387814f;
    const float H3  = 0.4886025119029199f;
    const float H15 = 1.0925484305920792f;
    const float Q5  = 0.31539156525252005f;
    const float Q15 = 0.5462742152960396f;
    float Y[9];
    Y[0] = Y00;
    Y[1] = H3 * st * sp;
    Y[2] = H3 * ct;
    Y[3] = H3 * st * cp;
    Y[4] = H15 * (st * cp) * (st * sp);
    Y[5] = H15 * (st * sp) * ct;
    Y[6] = Q5 * (3.f * ct * ct - 1.f);
    Y[7] = H15 * (st * cp) * ct;
    Y[8] = Q15 * ((st * cp) * (st * cp) - (st * sp) * (st * sp));

    // ---- this thread handles corners (dx, dy, z0) and (dx, dy, z1) ----
    const float* pp = pos + ((size_t)r * NS + s) * 3;
    const float x = pp[0], y = pp[1], z = pp[2];
    const float fx0 = floorf(x), fy0 = floorf(y), fz0 = floorf(z);
    const float fx = x - fx0, fy = y - fy0, fz = z - fz0;
    const int jx  = min(max((int)fx0 + dx, 0), GDIM - 1);
    const int jy  = min(max((int)fy0 + dy, 0), GDIM - 1);
    const int jz0 = min(max((int)fz0,      0), GDIM - 1);
    const int jz1 = min(max((int)fz0 + 1,  0), GDIM - 1);

    const float wxy = (dx ? fx : 1.f - fx) * (dy ? fy : 1.f - fy);
    const float wz0 = wxy * (1.f - fz);
    const float wz1 = wxy * fz;

    const float4* g0 = (const float4*)(grid + (((size_t)jx * GDIM + jy) * GDIM + jz0) * VD);
    const float4* g1 = (const float4*)(grid + (((size_t)jx * GDIM + jy) * GDIM + jz1) * VD);

    float f0[28], f1[28];
#pragma unroll
    for (int j = 0; j < 7; ++j) ((float4*)f0)[j] = g0[j];   // 14 independent loads
#pragma unroll
    for (int j = 0; j < 7; ++j) ((float4*)f1)[j] = g1[j];   // all in flight together

    float psig = wz0 * f0[0] + wz1 * f1[0];
    float d0r = 0.f, d0g = 0.f, d0b = 0.f;
    float d1r = 0.f, d1g = 0.f, d1b = 0.f;
#pragma unroll
    for (int n = 0; n < 9; ++n) {
        d0r += f0[1 + n]  * Y[n];
        d0g += f0[10 + n] * Y[n];
        d0b += f0[19 + n] * Y[n];
        d1r += f1[1 + n]  * Y[n];
        d1g += f1[10 + n] * Y[n];
        d1b += f1[19 + n] * Y[n];
    }
    const float pr = wz0 * d0r + wz1 * d1r;
    const float pg = wz0 * d0g + wz1 * d1g;
    const float pb = wz0 * d0b + wz1 * d1b;

    // ---- reduce the 4 corner-pair partials per sample ----
    __shared__ float4 part[512];
    part[tid] = make_float4(psig, pr, pg, pb);
    __syncthreads();

    __shared__ float wave0_total;
    __shared__ float fin[2][3];

    float t = 0.f, att = 0.f, rr = 0.f, rg = 0.f, rb = 0.f;
    if (tid < NS) {
        const float4 a = part[s];
        const float4 b = part[s + 128];
        const float4 c = part[s + 256];
        const float4 e = part[s + 384];
        const float sigma = a.x + b.x + c.x + e.x;
        rr = a.y + b.y + c.y + e.y;
        rg = a.z + b.z + c.z + e.z;
        rb = a.w + b.w + c.w + e.w;

        const float d = dist[(size_t)r * NS + s];
        att = expf(-sigma * d);

        // inclusive scan within each of the two waves
        t = att;
#pragma unroll
        for (int o = 1; o < 64; o <<= 1) {
            const float v = __shfl_up(t, (unsigned)o, 64);
            if (lane >= o) t += v;
        }
        if (tid == 63) wave0_total = t;
    }
    __syncthreads();

    if (tid < NS) {
        const float trans  = t + (tid >= 64 ? wave0_total : 0.f);
        const float weight = trans * (1.f - att);
        float a0 = weight * rr, a1 = weight * rg, a2 = weight * rb;
#pragma unroll
        for (int o = 32; o > 0; o >>= 1) {
            a0 += __shfl_down(a0, (unsigned)o, 64);
            a1 += __shfl_down(a1, (unsigned)o, 64);
            a2 += __shfl_down(a2, (unsigned)o, 64);
        }
        if (lane == 0) {
            const int wv = tid >> 6;
            fin[wv][0] = a0; fin[wv][1] = a1; fin[wv][2] = a2;
        }
    }
    __syncthreads();
    if (tid == 0) {
        out[(size_t)r * 3 + 0] = fin[0][0] + fin[1][0];
        out[(size_t)r * 3 + 1] = fin[0][1] + fin[1][1];
        out[(size_t)r * 3 + 2] = fin[0][2] + fin[1][2];
    }
}

extern "C" void kernel_launch(void* const* d_in, const int* in_sizes, int n_in,
                              void* d_out, int out_size, void* d_ws, size_t ws_size,
                              hipStream_t stream) {
    const float* grid = (const float*)d_in[0];
    const float* pos  = (const float*)d_in[1];
    const float* dst  = (const float*)d_in[2];
    const float* ang  = (const float*)d_in[3];
    float* out = (float*)d_out;

    const int R = in_sizes[3] / 2;   // 2048 rays
    plenoxel_kernel<<<R, 512, 0, stream>>>(grid, pos, dst, ang, out);
}